// Round 1
// baseline (291.231 us; speedup 1.0000x reference)
//
#include <hip/hip_runtime.h>
#include <math.h>

#define NB 256
#define NF 8
#define NS 200
#define ND 64
#define NH 36
#define EPSV 1e-3f
// ws float layout: [0,288) sum | [288,576) sumsq | [576,864) mean | [864,1152) inv_std

// Pass 1: per-(b,f) block computes h rows and accumulates per-(f,h) sum/sumsq.
__global__ __launch_bounds__(128) void k_stats(
    const float* __restrict__ query, const float* __restrict__ key,
    const float* __restrict__ W_h, const float* __restrict__ b_h,
    float* __restrict__ ws)
{
    const int blk = blockIdx.x;
    const int f = blk & (NF - 1);
    const int b = blk >> 3;
    const int tid = threadIdx.x;

    __shared__ float wkT[NH * ND];     // wkT[h][d] = W1[d][h] - W3[d][h]
    __shared__ float qrow[ND];
    __shared__ float qt[NH];
    __shared__ float part[2][2][NH];   // [sum|sq][wave][h]

    const float* Wf = W_h + (size_t)f * 3 * ND * NH;

    for (int i = tid; i < NH * ND; i += 128) {
        int h = i >> 6, d = i & 63;
        wkT[i] = Wf[d * NH + h] - Wf[(2 * ND + d) * NH + h];
    }
    if (tid < ND) qrow[tid] = query[((size_t)b * NF + f) * ND + tid];
    __syncthreads();
    if (tid < NH) {
        float acc = b_h[f * NH + tid];
        for (int d = 0; d < ND; ++d)
            acc += qrow[d] * (Wf[(ND + d) * NH + tid] + Wf[(2 * ND + d) * NH + tid]);
        qt[tid] = acc;
    }
    __syncthreads();

    const int s0 = 2 * tid;
    const bool v0 = (s0 < NS), v1 = (s0 + 1 < NS);
    const float* kbase = key + ((size_t)b * NF + f) * (size_t)(NS * ND);
    float k0[ND], k1[ND];
    {
        const float4* p0 = (const float4*)(kbase + (v0 ? s0 : 0) * ND);
        const float4* p1 = (const float4*)(kbase + (v1 ? (s0 + 1) : 0) * ND);
        #pragma unroll
        for (int j = 0; j < ND / 4; ++j) {
            float4 a = p0[j];
            k0[4*j+0]=a.x; k0[4*j+1]=a.y; k0[4*j+2]=a.z; k0[4*j+3]=a.w;
            float4 c = p1[j];
            k1[4*j+0]=c.x; k1[4*j+1]=c.y; k1[4*j+2]=c.z; k1[4*j+3]=c.w;
        }
    }
    const int wave = tid >> 6, lane = tid & 63;
    for (int h = 0; h < NH; ++h) {
        float a0 = qt[h], a1 = a0;
        const float4* wrow = (const float4*)(&wkT[h * ND]);
        #pragma unroll
        for (int j = 0; j < ND / 4; ++j) {
            float4 w = wrow[j];
            a0 += k0[4*j+0]*w.x + k0[4*j+1]*w.y + k0[4*j+2]*w.z + k0[4*j+3]*w.w;
            a1 += k1[4*j+0]*w.x + k1[4*j+1]*w.y + k1[4*j+2]*w.z + k1[4*j+3]*w.w;
        }
        if (!v0) a0 = 0.f;
        if (!v1) a1 = 0.f;
        float sv = a0 + a1;
        float sq = a0*a0 + a1*a1;
        #pragma unroll
        for (int off = 32; off; off >>= 1) {
            sv += __shfl_xor(sv, off, 64);
            sq += __shfl_xor(sq, off, 64);
        }
        if (lane == 0) { part[0][wave][h] = sv; part[1][wave][h] = sq; }
    }
    __syncthreads();
    if (tid < 2 * NH) {
        const int which = (tid >= NH) ? 1 : 0;
        const int h = tid - which * NH;
        const float tot = part[which][0][h] + part[which][1][h];
        atomicAdd(&ws[which * 288 + f * NH + h], tot);
    }
}

__global__ void k_finalize(float* __restrict__ ws) {
    const int t = blockIdx.x * blockDim.x + threadIdx.x;
    if (t < NF * NH) {
        const float inv_n = 1.f / (float)(NB * NS);
        const float m   = ws[t] * inv_n;
        const float var = ws[288 + t] * inv_n - m * m;
        ws[576 + t] = m;
        ws[864 + t] = rsqrtf(var + EPSV);
    }
}

// Pass 2: recompute h, normalize+gate, scores, masked softmax, attn@key.
__global__ __launch_bounds__(128) void k_attn(
    const float* __restrict__ query, const float* __restrict__ key,
    const float* __restrict__ W_h, const float* __restrict__ b_h,
    const float* __restrict__ alpha, const float* __restrict__ W_o,
    const float* __restrict__ b_o, const int* __restrict__ seqn,
    const float* __restrict__ ws, float* __restrict__ out)
{
    const int blk = blockIdx.x;
    const int f = blk & (NF - 1);
    const int b = blk >> 3;
    const int tid = threadIdx.x;

    __shared__ float wkT[NH * ND];
    __shared__ float qrow[ND];
    __shared__ float qt[NH];
    __shared__ float mean_s[NH], inv_s[NH], wo_s[NH];
    __shared__ float red[256];
    __shared__ float warr[256];
    __shared__ float pout[2][ND];

    const float* Wf = W_h + (size_t)f * 3 * ND * NH;
    for (int i = tid; i < NH * ND; i += 128) {
        int h = i >> 6, d = i & 63;
        wkT[i] = Wf[d * NH + h] - Wf[(2 * ND + d) * NH + h];
    }
    if (tid < ND) qrow[tid] = query[((size_t)b * NF + f) * ND + tid];
    if (tid >= 64 && tid < 64 + NH) {
        int h = tid - 64;
        mean_s[h] = ws[576 + f * NH + h];
        inv_s[h]  = ws[864 + f * NH + h];
        wo_s[h]   = W_o[f * NH + h];
    }
    __syncthreads();
    if (tid < NH) {
        float acc = b_h[f * NH + tid];
        for (int d = 0; d < ND; ++d)
            acc += qrow[d] * (Wf[(ND + d) * NH + tid] + Wf[(2 * ND + d) * NH + tid]);
        qt[tid] = acc;
    }
    __syncthreads();

    const float alf = alpha[f];
    const int sq_n = seqn[b * NF + f];
    const int s0 = 2 * tid;
    const bool v0 = (s0 < NS), v1 = (s0 + 1 < NS);
    const float* kbase = key + ((size_t)b * NF + f) * (size_t)(NS * ND);
    float k0[ND], k1[ND];
    {
        const float4* p0 = (const float4*)(kbase + (v0 ? s0 : 0) * ND);
        const float4* p1 = (const float4*)(kbase + (v1 ? (s0 + 1) : 0) * ND);
        #pragma unroll
        for (int j = 0; j < ND / 4; ++j) {
            float4 a = p0[j];
            k0[4*j+0]=a.x; k0[4*j+1]=a.y; k0[4*j+2]=a.z; k0[4*j+3]=a.w;
            float4 c = p1[j];
            k1[4*j+0]=c.x; k1[4*j+1]=c.y; k1[4*j+2]=c.z; k1[4*j+3]=c.w;
        }
    }
    float sc0 = b_o[f], sc1 = sc0;
    for (int h = 0; h < NH; ++h) {
        float a0 = qt[h], a1 = a0;
        const float4* wrow = (const float4*)(&wkT[h * ND]);
        #pragma unroll
        for (int j = 0; j < ND / 4; ++j) {
            float4 w = wrow[j];
            a0 += k0[4*j+0]*w.x + k0[4*j+1]*w.y + k0[4*j+2]*w.z + k0[4*j+3]*w.w;
            a1 += k1[4*j+0]*w.x + k1[4*j+1]*w.y + k1[4*j+2]*w.z + k1[4*j+3]*w.w;
        }
        const float mn = mean_s[h], iv = inv_s[h], wo = wo_s[h];
        const float p0 = 1.f / (1.f + __expf(-(a0 - mn) * iv));
        const float p1 = 1.f / (1.f + __expf(-(a1 - mn) * iv));
        sc0 += (alf + (1.f - alf) * p0) * a0 * wo;
        sc1 += (alf + (1.f - alf) * p1) * a1 * wo;
    }
    const bool m0v = v0 && (s0 < sq_n);
    const bool m1v = v1 && (s0 + 1 < sq_n);
    red[2 * tid]     = m0v ? sc0 : -1e30f;
    red[2 * tid + 1] = m1v ? sc1 : -1e30f;
    __syncthreads();
    for (int st = 128; st >= 1; st >>= 1) {
        if (tid < st) red[tid] = fmaxf(red[tid], red[tid + st]);
        __syncthreads();
    }
    const float maxv = red[0];
    __syncthreads();
    const float e0 = m0v ? __expf(sc0 - maxv) : 0.f;
    const float e1 = m1v ? __expf(sc1 - maxv) : 0.f;
    red[tid] = e0 + e1;
    __syncthreads();
    for (int st = 64; st >= 1; st >>= 1) {
        if (tid < st) red[tid] += red[tid + st];
        __syncthreads();
    }
    const float isum = 1.f / red[0];
    warr[s0]     = e0 * isum;
    warr[s0 + 1] = e1 * isum;
    __syncthreads();

    const int d = tid & 63, w2 = tid >> 6;  // 2 waves × 100 s each
    float acc = 0.f;
    for (int s = w2 * 100; s < w2 * 100 + 100; ++s)
        acc += warr[s] * kbase[s * ND + d];
    pout[w2][d] = acc;
    __syncthreads();
    if (tid < ND)
        out[((size_t)b * NF + f) * ND + tid] = pout[0][tid] + pout[1][tid];
}

extern "C" void kernel_launch(void* const* d_in, const int* in_sizes, int n_in,
                              void* d_out, int out_size, void* d_ws, size_t ws_size,
                              hipStream_t stream) {
    const float* query = (const float*)d_in[0];
    const float* key   = (const float*)d_in[1];
    const float* W_h   = (const float*)d_in[2];
    const float* b_h   = (const float*)d_in[3];
    const float* alpha = (const float*)d_in[4];
    const float* W_o   = (const float*)d_in[5];
    const float* b_o   = (const float*)d_in[6];
    const int*   seqn  = (const int*)d_in[7];
    float* out = (float*)d_out;
    float* ws  = (float*)d_ws;

    hipMemsetAsync(ws, 0, 576 * sizeof(float), stream);  // zero sum/sumsq accumulators
    k_stats<<<NB * NF, 128, 0, stream>>>(query, key, W_h, b_h, ws);
    k_finalize<<<1, 512, 0, stream>>>(ws);
    k_attn<<<NB * NF, 128, 0, stream>>>(query, key, W_h, b_h, alpha, W_o, b_o, seqn, ws, out);
}

// Round 2
// 250.141 us; speedup vs baseline: 1.1643x; 1.1643x over previous
//
#include <hip/hip_runtime.h>
#include <math.h>

#define NB 256
#define NF 8
#define NS 200
#define ND 64
#define NH 36
#define EPSV 1e-3f
#define LDA 72   // padded row stride in bf16 units (64 data + 8 pad) -> 2-way banks only
#define MT 13    // m-tiles of 16 rows covering 208 (>=200)
// ws float layout: [0,288) sum | [288,576) sumsq | [576,864) mean | [864,1152) inv_std

typedef __attribute__((ext_vector_type(8))) short short8;
typedef __attribute__((ext_vector_type(4))) short short4v;
typedef __attribute__((ext_vector_type(4))) float f32x4;

__device__ __forceinline__ unsigned short f32_to_bf16(float x) {
    unsigned u = __float_as_uint(x);
    unsigned r = u + 0x7FFFu + ((u >> 16) & 1u);   // round-to-nearest-even
    return (unsigned short)(r >> 16);
}
__device__ __forceinline__ float bf16_to_f32(unsigned short h) {
    return __uint_as_float(((unsigned)h) << 16);
}

template <bool STATS>
__global__ __launch_bounds__(256, 2) void k_main(
    const float* __restrict__ query, const float* __restrict__ key,
    const float* __restrict__ W_h, const float* __restrict__ b_h,
    const float* __restrict__ alpha, const float* __restrict__ W_o,
    const float* __restrict__ b_o, const int* __restrict__ seqn,
    float* __restrict__ ws, float* __restrict__ out)
{
    __shared__ __align__(16) unsigned short Ahi[208 * LDA];
    __shared__ __align__(16) unsigned short Alo[208 * LDA];
    __shared__ __align__(16) unsigned short Bt[48 * LDA];
    __shared__ float qrow[64];
    __shared__ float qt_s[48];
    __shared__ float meanP[48], invP[48], woP[48];
    __shared__ float sumP[48], sqP[48];
    __shared__ float scores[NS];
    __shared__ float warr[NS];
    __shared__ float red[256];
    __shared__ float pout[4][64];

    const int blk = blockIdx.x;
    const int f = blk & (NF - 1);
    const int b = blk >> 3;
    const int tid = threadIdx.x;
    const int lane = tid & 63;
    const int wv = tid >> 6;

    const float* Wf = W_h + (size_t)f * (3 * ND * NH);
    const float* kbase = key + (size_t)(b * NF + f) * (NS * ND);

    // ---- phase 1: small stages ----
    if (tid < 64) qrow[tid] = query[(size_t)(b * NF + f) * ND + tid];
    if (tid >= 64 && tid < 112) {
        int h = tid - 64;
        if (STATS) { sumP[h] = 0.f; sqP[h] = 0.f; }
        else if (h < NH) {
            meanP[h] = ws[576 + f * NH + h];
            invP[h]  = ws[864 + f * NH + h];
            woP[h]   = W_o[f * NH + h];
        } else { meanP[h] = 0.f; invP[h] = 0.f; woP[h] = 0.f; }
    }
    // B tile: wkT[h][d] = (W1 - W3)[d][h], bf16, zero-padded h in [36,48)
    for (int i = tid; i < 48 * 64; i += 256) {
        int h = i >> 6, d = i & 63;
        float v = (h < NH) ? (Wf[d * NH + h] - Wf[(2 * ND + d) * NH + h]) : 0.f;
        Bt[h * LDA + d] = f32_to_bf16(v);
    }
    __syncthreads();

    // ---- phase 2: A tile staging (hi/lo split), 13 outstanding loads/thread ----
    {
        const float4* kb4 = (const float4*)kbase;
        const int c = tid & 15;
        const int r0 = tid >> 4;
        float4 kv[MT];
        #pragma unroll
        for (int i = 0; i < MT; ++i) {
            int sr = r0 + 16 * i;
            kv[i] = (sr < NS) ? kb4[sr * 16 + c] : make_float4(0.f, 0.f, 0.f, 0.f);
        }
        #pragma unroll
        for (int i = 0; i < MT; ++i) {
            int sr = r0 + 16 * i;
            float vs[4] = {kv[i].x, kv[i].y, kv[i].z, kv[i].w};
            short4v h4, l4;
            #pragma unroll
            for (int j = 0; j < 4; ++j) {
                unsigned short hb = f32_to_bf16(vs[j]);
                float rem = vs[j] - bf16_to_f32(hb);
                h4[j] = (short)hb;
                l4[j] = (short)f32_to_bf16(rem);
            }
            *(short4v*)&Ahi[sr * LDA + 4 * c] = h4;
            *(short4v*)&Alo[sr * LDA + 4 * c] = l4;
        }
    }
    // qt[h] = b_h + q . (W2 + W3)[:,h]  (fp32 exact)
    if (tid < 48) {
        float acc = 0.f;
        if (tid < NH) {
            acc = b_h[f * NH + tid];
            for (int d = 0; d < ND; ++d)
                acc += qrow[d] * (Wf[(ND + d) * NH + tid] + Wf[(2 * ND + d) * NH + tid]);
        }
        qt_s[tid] = acc;
    }
    __syncthreads();

    // ---- MFMA phase ----
    const int col = lane & 15;
    const int quad = lane >> 4;
    const float alf = STATS ? 0.f : alpha[f];
    const float bo  = STATS ? 0.f : b_o[f];

    short8 bf[3][2];
    #pragma unroll
    for (int nt = 0; nt < 3; ++nt)
        #pragma unroll
        for (int ks = 0; ks < 2; ++ks)
            bf[nt][ks] = *(const short8*)&Bt[(nt * 16 + col) * LDA + ks * 32 + quad * 8];

    float s_sum[3] = {0.f, 0.f, 0.f}, s_sq[3] = {0.f, 0.f, 0.f};

    for (int mt = wv; mt < MT; mt += 4) {
        const int abase = (mt * 16 + col) * LDA + quad * 8;
        short8 ah0 = *(const short8*)&Ahi[abase];
        short8 ah1 = *(const short8*)&Ahi[abase + 32];
        short8 al0 = *(const short8*)&Alo[abase];
        short8 al1 = *(const short8*)&Alo[abase + 32];
        float part[4] = {0.f, 0.f, 0.f, 0.f};
        #pragma unroll
        for (int nt = 0; nt < 3; ++nt) {
            float qv = qt_s[nt * 16 + col];
            f32x4 acc = {qv, qv, qv, qv};
            acc = __builtin_amdgcn_mfma_f32_16x16x32_bf16(ah0, bf[nt][0], acc, 0, 0, 0);
            acc = __builtin_amdgcn_mfma_f32_16x16x32_bf16(ah1, bf[nt][1], acc, 0, 0, 0);
            acc = __builtin_amdgcn_mfma_f32_16x16x32_bf16(al0, bf[nt][0], acc, 0, 0, 0);
            acc = __builtin_amdgcn_mfma_f32_16x16x32_bf16(al1, bf[nt][1], acc, 0, 0, 0);
            if (STATS) {
                #pragma unroll
                for (int r = 0; r < 4; ++r) {
                    int s = mt * 16 + quad * 4 + r;
                    float v = (s < NS) ? acc[r] : 0.f;
                    s_sum[nt] += v;
                    s_sq[nt]  += v * v;
                }
            } else {
                float mn = meanP[nt * 16 + col], iv = invP[nt * 16 + col], wo = woP[nt * 16 + col];
                #pragma unroll
                for (int r = 0; r < 4; ++r) {
                    float h = acc[r];
                    float p = 1.f / (1.f + __expf(-(h - mn) * iv));
                    part[r] += (alf + (1.f - alf) * p) * h * wo;
                }
            }
        }
        if (!STATS) {
            #pragma unroll
            for (int r = 0; r < 4; ++r) {
                float v = part[r];
                v += __shfl_xor(v, 1, 64);
                v += __shfl_xor(v, 2, 64);
                v += __shfl_xor(v, 4, 64);
                v += __shfl_xor(v, 8, 64);
                if (col == 0) {
                    int s = mt * 16 + quad * 4 + r;
                    if (s < NS) scores[s] = v + bo;
                }
            }
        }
    }

    if (STATS) {
        #pragma unroll
        for (int nt = 0; nt < 3; ++nt) {
            float sv = s_sum[nt], qv = s_sq[nt];
            sv += __shfl_xor(sv, 16, 64); sv += __shfl_xor(sv, 32, 64);
            qv += __shfl_xor(qv, 16, 64); qv += __shfl_xor(qv, 32, 64);
            if (quad == 0 && wv == (nt & 3)) { /* spread atomics a bit */ }
            if (quad == 0) {
                atomicAdd(&sumP[nt * 16 + col], sv);
                atomicAdd(&sqP[nt * 16 + col], qv);
            }
        }
        __syncthreads();
        if (tid < NH) {
            atomicAdd(&ws[f * NH + tid], sumP[tid]);
            atomicAdd(&ws[288 + f * NH + tid], sqP[tid]);
        }
        return;
    }

    // ---- softmax over s ----
    __syncthreads();
    const int sq_n = seqn[b * NF + f];
    const bool val = (tid < NS) && (tid < sq_n);
    float sval = val ? scores[tid] : -1e30f;
    red[tid] = sval;
    __syncthreads();
    for (int st = 128; st >= 1; st >>= 1) {
        if (tid < st) red[tid] = fmaxf(red[tid], red[tid + st]);
        __syncthreads();
    }
    const float maxv = red[0];
    __syncthreads();
    float e = val ? __expf(sval - maxv) : 0.f;
    red[tid] = e;
    __syncthreads();
    for (int st = 128; st >= 1; st >>= 1) {
        if (tid < st) red[tid] += red[tid + st];
        __syncthreads();
    }
    const float isum = 1.f / red[0];
    if (tid < NS) warr[tid] = e * isum;
    __syncthreads();

    // ---- out = attn @ key (key reconstructed exactly from hi+lo) ----
    {
        const int d = lane;
        float acc = 0.f;
        for (int s = wv * 50; s < wv * 50 + 50; ++s) {
            float kvf = bf16_to_f32(Ahi[s * LDA + d]) + bf16_to_f32(Alo[s * LDA + d]);
            acc += warr[s] * kvf;
        }
        pout[wv][d] = acc;
    }
    __syncthreads();
    if (tid < 64)
        out[(size_t)(b * NF + f) * ND + tid] =
            pout[0][tid] + pout[1][tid] + pout[2][tid] + pout[3][tid];
}

__global__ void k_finalize(float* __restrict__ ws) {
    const int t = blockIdx.x * blockDim.x + threadIdx.x;
    if (t < NF * NH) {
        const float inv_n = 1.f / (float)(NB * NS);
        const float m   = ws[t] * inv_n;
        const float var = ws[288 + t] * inv_n - m * m;
        ws[576 + t] = m;
        ws[864 + t] = rsqrtf(var + EPSV);
    }
}

extern "C" void kernel_launch(void* const* d_in, const int* in_sizes, int n_in,
                              void* d_out, int out_size, void* d_ws, size_t ws_size,
                              hipStream_t stream) {
    const float* query = (const float*)d_in[0];
    const float* key   = (const float*)d_in[1];
    const float* W_h   = (const float*)d_in[2];
    const float* b_h   = (const float*)d_in[3];
    const float* alpha = (const float*)d_in[4];
    const float* W_o   = (const float*)d_in[5];
    const float* b_o   = (const float*)d_in[6];
    const int*   seqn  = (const int*)d_in[7];
    float* out = (float*)d_out;
    float* ws  = (float*)d_ws;

    hipMemsetAsync(ws, 0, 576 * sizeof(float), stream);
    k_main<true><<<NB * NF, 256, 0, stream>>>(query, key, W_h, b_h, alpha, W_o, b_o, seqn, ws, out);
    k_finalize<<<1, 512, 0, stream>>>(ws);
    k_main<false><<<NB * NF, 256, 0, stream>>>(query, key, W_h, b_h, alpha, W_o, b_o, seqn, ws, out);
}

// Round 3
// 213.146 us; speedup vs baseline: 1.3663x; 1.1736x over previous
//
#include <hip/hip_runtime.h>
#include <math.h>

#define NB 256
#define NF 8
#define NS 200
#define ND 64
#define NH 36
#define MT 13              // 13 m-tiles of 16 rows cover 208 >= 200
#define EPSV 1e-3f

// ws float-offset layout:
#define WS_SUM 0                      // [0,288)    per-(f,h) sum
#define WS_SQ  288                    // [288,576)  per-(f,h) sumsq
#define WS_QT  1152                   // 2048*48 floats: qt[b,f,h] (h padded to 48, 0 for h>=36)
#define WS_WK  (1152 + 2048 * 48)     // bf16 WkT[f][h(48)][d(64)] = (W1-W3)^T, 8*48*64 shorts

typedef __attribute__((ext_vector_type(8))) short short8;
typedef __attribute__((ext_vector_type(4))) float f32x4;

__device__ __forceinline__ unsigned short f32_to_bf16(float x) {
    unsigned u = __float_as_uint(x);
    unsigned r = u + 0x7FFFu + ((u >> 16) & 1u);   // round-to-nearest-even
    return (unsigned short)(r >> 16);
}
__device__ __forceinline__ float bf16_to_f32(unsigned short h) {
    return __uint_as_float(((unsigned)h) << 16);
}
__device__ __forceinline__ short8 cvt8(float4 a, float4 b) {
    short8 r;
    r[0] = (short)f32_to_bf16(a.x); r[1] = (short)f32_to_bf16(a.y);
    r[2] = (short)f32_to_bf16(a.z); r[3] = (short)f32_to_bf16(a.w);
    r[4] = (short)f32_to_bf16(b.x); r[5] = (short)f32_to_bf16(b.y);
    r[6] = (short)f32_to_bf16(b.z); r[7] = (short)f32_to_bf16(b.w);
    return r;
}

// blocks 0..255: qt[b,*,*] for b=blockIdx. blocks 256..263: WkT bf16 for f=blockIdx-256.
__global__ __launch_bounds__(256) void k_prep(
    const float* __restrict__ query, const float* __restrict__ W_h,
    const float* __restrict__ b_h, float* __restrict__ ws)
{
    const int blk = blockIdx.x, tid = threadIdx.x;
    if (blk < NB) {
        __shared__ float qs[NF * ND];
        for (int i = tid; i < NF * ND; i += 256)
            qs[i] = query[(size_t)blk * NF * ND + i];
        __syncthreads();
        for (int i = tid; i < NF * 48; i += 256) {
            int f = i / 48, h = i - f * 48;
            float acc = 0.f;
            if (h < NH) {
                const float* Wf = W_h + (size_t)f * (3 * ND * NH);
                acc = b_h[f * NH + h];
                for (int d = 0; d < ND; ++d)
                    acc += qs[f * ND + d] * (Wf[(ND + d) * NH + h] + Wf[(2 * ND + d) * NH + h]);
            }
            ws[WS_QT + (size_t)(blk * NF + f) * 48 + h] = acc;
        }
    } else {
        const int f = blk - NB;
        const float* Wf = W_h + (size_t)f * (3 * ND * NH);
        unsigned short* wk = (unsigned short*)(ws + WS_WK) + f * (48 * ND);
        for (int i = tid; i < 48 * ND; i += 256) {
            int h = i >> 6, d = i & 63;
            float v = (h < NH) ? (Wf[d * NH + h] - Wf[(2 * ND + d) * NH + h]) : 0.f;
            wk[h * ND + d] = f32_to_bf16(v);
        }
    }
}

__global__ __launch_bounds__(256, 4) void k_stats(
    const float* __restrict__ key, float* __restrict__ ws)
{
    const int blk = blockIdx.x;           // = b*NF + f
    const int f = blk & (NF - 1);
    const int tid = threadIdx.x;
    const int lane = tid & 63;
    const int wv = tid >> 6;
    const int col = lane & 15;
    const int quad = lane >> 4;

    __shared__ float sumP[48], sqP[48];
    if (tid < 48) { sumP[tid] = 0.f; sqP[tid] = 0.f; }
    __syncthreads();

    const float* kbase = key + (size_t)blk * (NS * ND);
    const unsigned short* wk = (const unsigned short*)(ws + WS_WK) + f * (48 * ND);

    short8 bfr[3][2];
    float qv[3];
    #pragma unroll
    for (int nt = 0; nt < 3; ++nt) {
        #pragma unroll
        for (int ks = 0; ks < 2; ++ks)
            bfr[nt][ks] = *(const short8*)&wk[(nt * 16 + col) * ND + ks * 32 + quad * 8];
        qv[nt] = ws[WS_QT + (size_t)blk * 48 + nt * 16 + col];
    }

    float s_sum[3] = {0.f, 0.f, 0.f}, s_sq[3] = {0.f, 0.f, 0.f};
    for (int mt = wv; mt < MT; mt += 4) {
        const int s = 16 * mt + col;
        const float4* p = (const float4*)(kbase + (size_t)(s < NS ? s : NS - 1) * ND + quad * 8);
        float4 a0 = p[0], a1 = p[1];      // d = quad*8 .. +7
        float4 b0 = p[8], b1 = p[9];      // d = 32+quad*8 .. +7
        short8 ah0 = cvt8(a0, a1);
        short8 ah1 = cvt8(b0, b1);
        #pragma unroll
        for (int nt = 0; nt < 3; ++nt) {
            f32x4 acc = {qv[nt], qv[nt], qv[nt], qv[nt]};
            acc = __builtin_amdgcn_mfma_f32_16x16x32_bf16(ah0, bfr[nt][0], acc, 0, 0, 0);
            acc = __builtin_amdgcn_mfma_f32_16x16x32_bf16(ah1, bfr[nt][1], acc, 0, 0, 0);
            #pragma unroll
            for (int r = 0; r < 4; ++r) {
                int srow = 16 * mt + quad * 4 + r;
                if (srow < NS) { float v = acc[r]; s_sum[nt] += v; s_sq[nt] += v * v; }
            }
        }
    }
    #pragma unroll
    for (int nt = 0; nt < 3; ++nt) {
        float sv = s_sum[nt], qq = s_sq[nt];
        sv += __shfl_xor(sv, 16, 64); sv += __shfl_xor(sv, 32, 64);
        qq += __shfl_xor(qq, 16, 64); qq += __shfl_xor(qq, 32, 64);
        if (quad == 0) {
            atomicAdd(&sumP[nt * 16 + col], sv);
            atomicAdd(&sqP[nt * 16 + col], qq);
        }
    }
    __syncthreads();
    if (tid < NH) {
        atomicAdd(&ws[WS_SUM + f * NH + tid], sumP[tid]);
        atomicAdd(&ws[WS_SQ + f * NH + tid], sqP[tid]);
    }
}

__global__ __launch_bounds__(256, 3) void k_attn(
    const float* __restrict__ key, const float* __restrict__ alpha,
    const float* __restrict__ W_o, const float* __restrict__ b_o,
    const int* __restrict__ seqn, const float* __restrict__ ws,
    float* __restrict__ out)
{
    const int blk = blockIdx.x;           // = b*NF + f
    const int f = blk & (NF - 1);
    const int tid = threadIdx.x;
    const int lane = tid & 63;
    const int wv = tid >> 6;
    const int col = lane & 15;
    const int quad = lane >> 4;

    __shared__ float sw[208];             // scores, then softmax weights
    __shared__ float redM[4], redS[4];
    __shared__ float pout[4][64];

    const float* kbase = key + (size_t)blk * (NS * ND);
    const unsigned short* wk = (const unsigned short*)(ws + WS_WK) + f * (48 * ND);
    const float inv_n = 1.f / (float)(NB * NS);

    short8 bfr[3][2];
    float qv[3], mn[3], iv[3], wo[3];
    #pragma unroll
    for (int nt = 0; nt < 3; ++nt) {
        #pragma unroll
        for (int ks = 0; ks < 2; ++ks)
            bfr[nt][ks] = *(const short8*)&wk[(nt * 16 + col) * ND + ks * 32 + quad * 8];
        const int hh = nt * 16 + col;
        const bool hv = hh < NH;
        const int hc = hv ? hh : 0;
        qv[nt] = ws[WS_QT + (size_t)blk * 48 + hh];
        const float sm = ws[WS_SUM + f * NH + hc];
        const float sq = ws[WS_SQ + f * NH + hc];
        const float m = sm * inv_n;
        mn[nt] = m;
        iv[nt] = rsqrtf(fmaxf(sq * inv_n - m * m, 0.f) + EPSV);
        wo[nt] = hv ? W_o[f * NH + hh] : 0.f;
    }
    const float alf = alpha[f];
    const float bo = b_o[f];
    const int sq_n = seqn[blk];

    short8 kah[4][2];                     // retained key fragments (bf16)
    #pragma unroll
    for (int t = 0; t < 4; ++t) {
        const int mt = wv + 4 * t;
        if (mt < MT) {
            const int s = 16 * mt + col;
            const float4* p = (const float4*)(kbase + (size_t)(s < NS ? s : NS - 1) * ND + quad * 8);
            float4 a0 = p[0], a1 = p[1];
            float4 b0 = p[8], b1 = p[9];
            kah[t][0] = cvt8(a0, a1);
            kah[t][1] = cvt8(b0, b1);
            float part[4] = {0.f, 0.f, 0.f, 0.f};
            #pragma unroll
            for (int nt = 0; nt < 3; ++nt) {
                f32x4 acc = {qv[nt], qv[nt], qv[nt], qv[nt]};
                acc = __builtin_amdgcn_mfma_f32_16x16x32_bf16(kah[t][0], bfr[nt][0], acc, 0, 0, 0);
                acc = __builtin_amdgcn_mfma_f32_16x16x32_bf16(kah[t][1], bfr[nt][1], acc, 0, 0, 0);
                #pragma unroll
                for (int r = 0; r < 4; ++r) {
                    const float h = acc[r];
                    const float pg = 1.f / (1.f + __expf(-(h - mn[nt]) * iv[nt]));
                    part[r] += (alf + (1.f - alf) * pg) * h * wo[nt];
                }
            }
            #pragma unroll
            for (int r = 0; r < 4; ++r) {
                float v = part[r];
                v += __shfl_xor(v, 1, 64);
                v += __shfl_xor(v, 2, 64);
                v += __shfl_xor(v, 4, 64);
                v += __shfl_xor(v, 8, 64);
                const int srow = 16 * mt + quad * 4 + r;
                if (col == 0 && srow < NS) sw[srow] = v + bo;
            }
        }
    }
    __syncthreads();

    // softmax over s
    const bool valid = (tid < 208) && (tid < sq_n);
    const float sc = valid ? sw[tid] : -1e30f;
    float m = sc;
    m = fmaxf(m, __shfl_xor(m, 1, 64));  m = fmaxf(m, __shfl_xor(m, 2, 64));
    m = fmaxf(m, __shfl_xor(m, 4, 64));  m = fmaxf(m, __shfl_xor(m, 8, 64));
    m = fmaxf(m, __shfl_xor(m, 16, 64)); m = fmaxf(m, __shfl_xor(m, 32, 64));
    if (lane == 0) redM[wv] = m;
    __syncthreads();
    const float maxv = fmaxf(fmaxf(redM[0], redM[1]), fmaxf(redM[2], redM[3]));
    const float e = valid ? __expf(sc - maxv) : 0.f;
    float l = e;
    l += __shfl_xor(l, 1, 64);  l += __shfl_xor(l, 2, 64);
    l += __shfl_xor(l, 4, 64);  l += __shfl_xor(l, 8, 64);
    l += __shfl_xor(l, 16, 64); l += __shfl_xor(l, 32, 64);
    if (lane == 0) redS[wv] = l;
    __syncthreads();
    const float isum = 1.f / (redS[0] + redS[1] + redS[2] + redS[3]);
    if (tid < 208) sw[tid] = e * isum;
    __syncthreads();

    // out = attn @ key, from retained bf16 fragments
    float po0[8] = {0,0,0,0,0,0,0,0}, po1[8] = {0,0,0,0,0,0,0,0};
    #pragma unroll
    for (int t = 0; t < 4; ++t) {
        const int mt = wv + 4 * t;
        if (mt < MT) {
            const float w = sw[16 * mt + col];
            #pragma unroll
            for (int j = 0; j < 8; ++j) {
                po0[j] += w * bf16_to_f32((unsigned short)kah[t][0][j]);
                po1[j] += w * bf16_to_f32((unsigned short)kah[t][1][j]);
            }
        }
    }
    #pragma unroll
    for (int off = 1; off <= 8; off <<= 1) {
        #pragma unroll
        for (int j = 0; j < 8; ++j) {
            po0[j] += __shfl_xor(po0[j], off, 64);
            po1[j] += __shfl_xor(po1[j], off, 64);
        }
    }
    if (col == 0) {
        #pragma unroll
        for (int j = 0; j < 8; ++j) {
            pout[wv][quad * 8 + j] = po0[j];
            pout[wv][32 + quad * 8 + j] = po1[j];
        }
    }
    __syncthreads();
    if (tid < 64)
        out[(size_t)blk * ND + tid] =
            pout[0][tid] + pout[1][tid] + pout[2][tid] + pout[3][tid];
}

extern "C" void kernel_launch(void* const* d_in, const int* in_sizes, int n_in,
                              void* d_out, int out_size, void* d_ws, size_t ws_size,
                              hipStream_t stream) {
    const float* query = (const float*)d_in[0];
    const float* key   = (const float*)d_in[1];
    const float* W_h   = (const float*)d_in[2];
    const float* b_h   = (const float*)d_in[3];
    const float* alpha = (const float*)d_in[4];
    const float* W_o   = (const float*)d_in[5];
    const float* b_o   = (const float*)d_in[6];
    const int*   seqn  = (const int*)d_in[7];
    float* out = (float*)d_out;
    float* ws  = (float*)d_ws;

    hipMemsetAsync(ws, 0, 576 * sizeof(float), stream);   // zero sum/sumsq
    k_prep<<<NB + NF, 256, 0, stream>>>(query, W_h, b_h, ws);
    k_stats<<<NB * NF, 256, 0, stream>>>(key, ws);
    k_attn<<<NB * NF, 256, 0, stream>>>(key, alpha, W_o, b_o, seqn, ws, out);
}